// Round 4
// baseline (291.471 us; speedup 1.0000x reference)
//
#include <hip/hip_runtime.h>
#include <hip/hip_bf16.h>

#define LN_EPS 1e-5f

static __device__ __forceinline__ float readlane_f(float v, int lane) {
    return __int_as_float(__builtin_amdgcn_readlane(__float_as_int(v), lane));
}

// ---------------------------------------------------------------------------
// Kernel A: per-token-id key table. key[v] = LN(e_v + FF(e_v)), v in [0,64).
// ---------------------------------------------------------------------------
__global__ __launch_bounds__(64) void build_keys(
    const float* __restrict__ embed,   // 64x64
    const float* __restrict__ w1,      // 64x128
    const float* __restrict__ b1,      // 128
    const float* __restrict__ w2,      // 128x64
    const float* __restrict__ b2,      // 64
    const float* __restrict__ lnw,     // 64
    const float* __restrict__ lnb,     // 64
    float* __restrict__ keytab)        // 64x64 out
{
    const int v = blockIdx.x, lane = threadIdx.x;
    __shared__ float se[64];
    __shared__ float sh[128];
    se[lane] = embed[v * 64 + lane];
    __syncthreads();
    float h0 = b1[lane];
    float h1 = b1[lane + 64];
    #pragma unroll 8
    for (int i = 0; i < 64; ++i) {
        float e = se[i];
        h0 = fmaf(e, w1[i * 128 + lane], h0);
        h1 = fmaf(e, w1[i * 128 + lane + 64], h1);
    }
    sh[lane]      = fmaxf(h0, 0.f);
    sh[lane + 64] = fmaxf(h1, 0.f);
    __syncthreads();
    float acc = b2[lane];
    #pragma unroll 8
    for (int j = 0; j < 128; ++j)
        acc = fmaf(sh[j], w2[j * 64 + lane], acc);
    float pre = se[lane] + acc;
    float sum = pre;
    #pragma unroll
    for (int off = 32; off >= 1; off >>= 1) sum += __shfl_xor(sum, off, 64);
    float mu  = sum * (1.f / 64.f);
    float dev = pre - mu;
    float sq  = dev * dev;
    #pragma unroll
    for (int off = 32; off >= 1; off >>= 1) sq += __shfl_xor(sq, off, 64);
    float var = sq * (1.f / 64.f);
    float key = dev * (1.f / sqrtf(var + LN_EPS)) * lnw[lane] + lnb[lane];
    keytab[v * 64 + lane] = key;
}

// ---------------------------------------------------------------------------
// Kernel B: Gram tables (Ghat stored NEGATED) + fused output weight.
// ---------------------------------------------------------------------------
__global__ __launch_bounds__(64) void build_tables(
    const float* __restrict__ keytab,
    const float* __restrict__ read_w,
    const float* __restrict__ read_b,
    const float* __restrict__ out_w,
    const float* __restrict__ out_b,
    float* __restrict__ Gg,
    float* __restrict__ GhatN,   // negated: -beta_w * G[w][u]
    float* __restrict__ Wc,
    float* __restrict__ biasv)
{
    const int w = blockIdx.x, lane = threadIdx.x;
    __shared__ float sk[64 * 65];
    __shared__ float srw[64];
    #pragma unroll 8
    for (int r = 0; r < 64; ++r) sk[r * 65 + lane] = keytab[r * 64 + lane];
    srw[lane] = read_w[w * 64 + lane];
    __syncthreads();
    float g = 0.f;
    #pragma unroll 8
    for (int i = 0; i < 64; ++i)
        g = fmaf(sk[w * 65 + i], sk[lane * 65 + i], g);
    float gww  = readlane_f(g, w);
    float beta = 1.f / (gww + 1e-6f);
    Gg[w * 64 + lane]    = g;
    GhatN[w * 64 + lane] = -(beta * g);
    float acc = 0.f;
    #pragma unroll 8
    for (int j = 0; j < 64; ++j)
        acc = fmaf(srw[j], out_w[j * 64 + lane], acc);
    Wc[w * 64 + lane] = acc;
    if (w == 0) {
        float bacc = out_b[lane];
        #pragma unroll 8
        for (int j = 0; j < 64; ++j)
            bacc = fmaf(read_b[j], out_w[j * 64 + lane], bacc);
        biasv[lane] = bacc;
    }
}

// ---------------------------------------------------------------------------
// Kernel C: dual-space backward delta scan, TWO batches per wave.
// Backward over t = 4094..0:  s_t = d[w_t]; c[w_t] += s_t; d += s_t*GhatN[w_t]
// One wave = 64 lanes = one batch's d vector; two independent batch states
// (A,B) interleaved in one instruction stream so each batch's hazard/wait
// windows (v_fmac->v_readlane, readlane->SGPR-use, lgkm) are filled by the
// other batch's instructions. The per-step boundary ternary folds at compile
// time (j is an unroll constant).
// ---------------------------------------------------------------------------
__global__ __launch_bounds__(64) void delta_scan(
    const int*   __restrict__ seq,     // B x 4096
    const float* __restrict__ Gg,      // 64x64
    const float* __restrict__ GhatN,   // 64x64 (negated)
    const float* __restrict__ keytab,  // 64x64
    const float* __restrict__ Wc,      // 64x64
    const float* __restrict__ biasv,   // 64
    float* __restrict__ out)           // B x 64
{
    const int lane = threadIdx.x;
    const int bA   = 2 * blockIdx.x;
    const int bB   = bA + 1;
    __shared__ float sG[64 * 64];   // negated Ghat rows (shared by both batches)
    __shared__ float sC[2][64];
    __shared__ float sCtx[2][64];
    #pragma unroll 8
    for (int r = 0; r < 64; ++r) sG[r * 64 + lane] = GhatN[r * 64 + lane];
    const int* seqA = seq + (size_t)bA * 4096;
    const int* seqB = seq + (size_t)bB * 4096;
    float dA = Gg[seqA[4095] * 64 + lane];
    float dB = Gg[seqB[4095] * 64 + lane];
    __syncthreads();

    float cA = 0.f, sA = 0.f, ghA = 0.f;
    float cB = 0.f, sB = 0.f, ghB = 0.f;
    int vcA = seqA[64 * 63 + lane];            // top block tokens: t = 4032+lane
    int vcB = seqB[64 * 63 + lane];
    float qA[9], qB[9];                        // depth-9 LDS row prefetch queues
    #pragma unroll
    for (int k = 0; k < 9; ++k) {
        int wa = __builtin_amdgcn_readlane(vcA, 62 - k);
        int wb = __builtin_amdgcn_readlane(vcB, 62 - k);
        qA[k] = sG[wa * 64 + lane];
        qB[k] = sG[wb * 64 + lane];
    }

    #pragma unroll 1
    for (int blk = 64; blk >= 0; --blk) {
        int vnA = (blk > 0) ? seqA[(blk - 1) * 63 + lane] : vcA;
        int vnB = (blk > 0) ? seqB[(blk - 1) * 63 + lane] : vcB;
        #pragma unroll
        for (int j = 62; j >= 0; --j) {        // t = blk*63 + j, descending
            const int slot = (62 - j) % 9;
            const int jl   = j - 9;            // prefetch target (compile-time)
            {   // batch A
                int   w0 = __builtin_amdgcn_readlane(vcA, j);
                float p  = readlane_f(dA,  w0);     // stale d at lane w_t
                float g  = readlane_f(ghA, w0);     // -Ghat[w_{t+1}][w_t]
                float s0 = fmaf(sA, g, p);          // exact s_t
                dA = fmaf(sA, ghA, dA);             // deferred step-(t+1) update
                cA += (lane == w0) ? s0 : 0.f;
                float rn = qA[slot];
                int wpre = (jl >= 0) ? __builtin_amdgcn_readlane(vcA, jl)
                                     : __builtin_amdgcn_readlane(vnA, jl + 63);
                qA[slot] = sG[wpre * 64 + lane];
                sA = s0; ghA = rn;
            }
            {   // batch B
                int   w0 = __builtin_amdgcn_readlane(vcB, j);
                float p  = readlane_f(dB,  w0);
                float g  = readlane_f(ghB, w0);
                float s0 = fmaf(sB, g, p);
                dB = fmaf(sB, ghB, dB);
                cB += (lane == w0) ? s0 : 0.f;
                float rn = qB[slot];
                int wpre = (jl >= 0) ? __builtin_amdgcn_readlane(vcB, jl)
                                     : __builtin_amdgcn_readlane(vnB, jl + 63);
                qB[slot] = sG[wpre * 64 + lane];
                sB = s0; ghB = rn;
            }
        }
        vcA = vnA; vcB = vnB;
    }

    // ctx = sum_v c_v * key_v ; out = ctx @ Wc + bias   (both batches)
    sC[0][lane] = cA;
    sC[1][lane] = cB;
    __syncthreads();
    float ctxA = 0.f, ctxB = 0.f;
    #pragma unroll 8
    for (int v = 0; v < 64; ++v) {
        float kv = keytab[v * 64 + lane];
        ctxA = fmaf(sC[0][v], kv, ctxA);
        ctxB = fmaf(sC[1][v], kv, ctxB);
    }
    sCtx[0][lane] = ctxA;
    sCtx[1][lane] = ctxB;
    __syncthreads();
    float oA = biasv[lane], oB = oA;
    #pragma unroll 8
    for (int i = 0; i < 64; ++i) {
        float wv = Wc[i * 64 + lane];
        oA = fmaf(sCtx[0][i], wv, oA);
        oB = fmaf(sCtx[1][i], wv, oB);
    }
    out[(size_t)bA * 64 + lane] = oA;
    out[(size_t)bB * 64 + lane] = oB;
}

extern "C" void kernel_launch(void* const* d_in, const int* in_sizes, int n_in,
                              void* d_out, int out_size, void* d_ws, size_t ws_size,
                              hipStream_t stream) {
    const int*   seq    = (const int*)d_in[0];
    const float* embed  = (const float*)d_in[1];
    const float* ff_w1  = (const float*)d_in[2];
    const float* ff_b1  = (const float*)d_in[3];
    const float* ff_w2  = (const float*)d_in[4];
    const float* ff_b2  = (const float*)d_in[5];
    const float* ln_w   = (const float*)d_in[6];
    const float* ln_b   = (const float*)d_in[7];
    const float* read_w = (const float*)d_in[8];
    const float* read_b = (const float*)d_in[9];
    const float* out_w  = (const float*)d_in[10];
    const float* out_b  = (const float*)d_in[11];
    float* out = (float*)d_out;

    float* wsf    = (float*)d_ws;
    float* keytab = wsf;            // 4096
    float* Gg     = wsf + 4096;     // 4096
    float* GhatN  = wsf + 8192;     // 4096
    float* Wc     = wsf + 12288;    // 4096
    float* biasv  = wsf + 16384;    // 64

    build_keys<<<64, 64, 0, stream>>>(embed, ff_w1, ff_b1, ff_w2, ff_b2, ln_w, ln_b, keytab);
    build_tables<<<64, 64, 0, stream>>>(keytab, read_w, read_b, out_w, out_b,
                                        Gg, GhatN, Wc, biasv);
    delta_scan<<<128, 64, 0, stream>>>(seq, Gg, GhatN, keytab, Wc, biasv, out);
}

// Round 6
// 168.280 us; speedup vs baseline: 1.7321x; 1.7321x over previous
//
#include <hip/hip_runtime.h>
#include <hip/hip_bf16.h>

#define LN_EPS 1e-5f

static __device__ __forceinline__ float readlane_f(float v, int lane) {
    return __int_as_float(__builtin_amdgcn_readlane(__float_as_int(v), lane));
}
// v_writelane_b32: set lane `lane_imm` of dst to uniform value `val`.
// (__builtin_amdgcn_writelane is not exposed on this ROCm; ISA instr is.)
static __device__ __forceinline__ void writelane_f(int& dst, float val, int lane_imm) {
    asm volatile("v_writelane_b32 %0, %1, %2"
                 : "+v"(dst)
                 : "s"(__float_as_int(val)), "i"(lane_imm));
}

// ---------------------------------------------------------------------------
// Kernel A: per-token-id key table. key[v] = LN(e_v + FF(e_v)), v in [0,64).
// ---------------------------------------------------------------------------
__global__ __launch_bounds__(64) void build_keys(
    const float* __restrict__ embed,   // 64x64
    const float* __restrict__ w1,      // 64x128
    const float* __restrict__ b1,      // 128
    const float* __restrict__ w2,      // 128x64
    const float* __restrict__ b2,      // 64
    const float* __restrict__ lnw,     // 64
    const float* __restrict__ lnb,     // 64
    float* __restrict__ keytab)        // 64x64 out
{
    const int v = blockIdx.x, lane = threadIdx.x;
    __shared__ float se[64];
    __shared__ float sh[128];
    se[lane] = embed[v * 64 + lane];
    __syncthreads();
    float h0 = b1[lane];
    float h1 = b1[lane + 64];
    #pragma unroll 8
    for (int i = 0; i < 64; ++i) {
        float e = se[i];
        h0 = fmaf(e, w1[i * 128 + lane], h0);
        h1 = fmaf(e, w1[i * 128 + lane + 64], h1);
    }
    sh[lane]      = fmaxf(h0, 0.f);
    sh[lane + 64] = fmaxf(h1, 0.f);
    __syncthreads();
    float acc = b2[lane];
    #pragma unroll 8
    for (int j = 0; j < 128; ++j)
        acc = fmaf(sh[j], w2[j * 64 + lane], acc);
    float pre = se[lane] + acc;
    float sum = pre;
    #pragma unroll
    for (int off = 32; off >= 1; off >>= 1) sum += __shfl_xor(sum, off, 64);
    float mu  = sum * (1.f / 64.f);
    float dev = pre - mu;
    float sq  = dev * dev;
    #pragma unroll
    for (int off = 32; off >= 1; off >>= 1) sq += __shfl_xor(sq, off, 64);
    float var = sq * (1.f / 64.f);
    float key = dev * (1.f / sqrtf(var + LN_EPS)) * lnw[lane] + lnb[lane];
    keytab[v * 64 + lane] = key;
}

// ---------------------------------------------------------------------------
// Kernel B: Gram tables (Ghat stored NEGATED) + fused output weight.
// ---------------------------------------------------------------------------
__global__ __launch_bounds__(64) void build_tables(
    const float* __restrict__ keytab,
    const float* __restrict__ read_w,
    const float* __restrict__ read_b,
    const float* __restrict__ out_w,
    const float* __restrict__ out_b,
    float* __restrict__ Gg,
    float* __restrict__ GhatN,   // negated: -beta_w * G[w][u]
    float* __restrict__ Wc,
    float* __restrict__ biasv)
{
    const int w = blockIdx.x, lane = threadIdx.x;
    __shared__ float sk[64 * 65];
    __shared__ float srw[64];
    #pragma unroll 8
    for (int r = 0; r < 64; ++r) sk[r * 65 + lane] = keytab[r * 64 + lane];
    srw[lane] = read_w[w * 64 + lane];
    __syncthreads();
    float g = 0.f;
    #pragma unroll 8
    for (int i = 0; i < 64; ++i)
        g = fmaf(sk[w * 65 + i], sk[lane * 65 + i], g);
    float gww  = readlane_f(g, w);
    float beta = 1.f / (gww + 1e-6f);
    Gg[w * 64 + lane]    = g;
    GhatN[w * 64 + lane] = -(beta * g);
    float acc = 0.f;
    #pragma unroll 8
    for (int j = 0; j < 64; ++j)
        acc = fmaf(srw[j], out_w[j * 64 + lane], acc);
    Wc[w * 64 + lane] = acc;
    if (w == 0) {
        float bacc = out_b[lane];
        #pragma unroll 8
        for (int j = 0; j < 64; ++j)
            bacc = fmaf(read_b[j], out_w[j * 64 + lane], bacc);
        biasv[lane] = bacc;
    }
}

// ---------------------------------------------------------------------------
// Kernel C: dual-space backward delta scan. One wave per batch, lean body.
// Backward over t = 4094..0:  s_t = d[w_t]; d += s_t*GhatN[w_t]; c[w_t] += s_t
// Per step: 1 readlane (token, 21 steps ahead -> doubles as prefetch index
// and, via rotating SGPR queue wq[21], as the step's lane-select with no
// fresh-SGPR hazard), 1 readlane (p), 1 fmac (d), 1 writelane (pack s by
// step index), 1 ds_read (depth-21 row prefetch; 63%21==0). c-scatter is one
// ds_add_f32 per 63-block using the lane-indexed token vector.
// ---------------------------------------------------------------------------
__global__ __launch_bounds__(64) void delta_scan(
    const int*   __restrict__ seq,     // B x 4096
    const float* __restrict__ Gg,      // 64x64
    const float* __restrict__ GhatN,   // 64x64 (negated)
    const float* __restrict__ keytab,  // 64x64
    const float* __restrict__ Wc,      // 64x64
    const float* __restrict__ biasv,   // 64
    float* __restrict__ out)           // B x 64
{
    const int lane = threadIdx.x;
    const int b    = blockIdx.x;
    __shared__ float sG[64 * 64];   // negated Ghat rows
    __shared__ float sc[64];        // c bins
    __shared__ float sCtx[64];
    #pragma unroll 8
    for (int r = 0; r < 64; ++r) sG[r * 64 + lane] = GhatN[r * 64 + lane];
    sc[lane] = 0.f;
    const int* seqb = seq + (size_t)b * 4096;
    float d = Gg[seqb[4095] * 64 + lane];   // d_v = G[w_query][v]
    __syncthreads();

    int vS = 0;                       // packed s_t bits, lane = j (lane 63 stays 0)
    int vcur = seqb[64 * 63 + lane];  // top chunk tokens: t = 4032+lane
    int   wq[21];                     // rotating token queue (SGPR, uniform)
    float q_[21];                     // rotating GhatN-row queue (prefetched rows)
    #pragma unroll
    for (int s = 0; s < 21; ++s) {
        wq[s] = __builtin_amdgcn_readlane(vcur, 62 - s);
        q_[s] = sG[wq[s] * 64 + lane];
    }

    #pragma unroll 1
    for (int blk = 64; blk >= 0; --blk) {
        int vnext = (blk > 0) ? seqb[(blk - 1) * 63 + lane] : vcur;
        #pragma unroll
        for (int j = 62; j >= 0; --j) {        // t = blk*63 + j, descending
            const int slot = (62 - j) % 21;
            const int jl   = j - 21;           // compile-time after unroll
            int   w0 = wq[slot];               // token for THIS step (21-old SGPR)
            float p  = readlane_f(d, w0);      // s_t = d[w_t]
            d = fmaf(p, q_[slot], d);          // d += s_t * GhatN[w_t]  (row prefetched)
            writelane_f(vS, p, j);             // pack s_t at lane j
            int wn = (jl >= 0) ? __builtin_amdgcn_readlane(vcur, jl)
                               : __builtin_amdgcn_readlane(vnext, jl + 63);
            wq[slot] = wn;                     // token for step jl (used in 21 steps)
            q_[slot] = sG[wn * 64 + lane];     // prefetch its GhatN row
        }
        // scatter this chunk's 63 s-values into c bins (lane 63 adds 0.0)
        atomicAdd(&sc[vcur & 63], __int_as_float(vS));
        vS = 0;
        vcur = vnext;
    }
    __syncthreads();

    // ctx = sum_v c_v * key_v ; out = ctx @ Wc + bias
    float ctx = 0.f;
    #pragma unroll 8
    for (int v = 0; v < 64; ++v)
        ctx = fmaf(sc[v], keytab[v * 64 + lane], ctx);
    sCtx[lane] = ctx;
    __syncthreads();
    float o = biasv[lane];
    #pragma unroll 8
    for (int i = 0; i < 64; ++i)
        o = fmaf(sCtx[i], Wc[i * 64 + lane], o);
    out[(size_t)b * 64 + lane] = o;
}

extern "C" void kernel_launch(void* const* d_in, const int* in_sizes, int n_in,
                              void* d_out, int out_size, void* d_ws, size_t ws_size,
                              hipStream_t stream) {
    const int*   seq    = (const int*)d_in[0];
    const float* embed  = (const float*)d_in[1];
    const float* ff_w1  = (const float*)d_in[2];
    const float* ff_b1  = (const float*)d_in[3];
    const float* ff_w2  = (const float*)d_in[4];
    const float* ff_b2  = (const float*)d_in[5];
    const float* ln_w   = (const float*)d_in[6];
    const float* ln_b   = (const float*)d_in[7];
    const float* read_w = (const float*)d_in[8];
    const float* read_b = (const float*)d_in[9];
    const float* out_w  = (const float*)d_in[10];
    const float* out_b  = (const float*)d_in[11];
    float* out = (float*)d_out;

    float* wsf    = (float*)d_ws;
    float* keytab = wsf;            // 4096
    float* Gg     = wsf + 4096;     // 4096
    float* GhatN  = wsf + 8192;     // 4096
    float* Wc     = wsf + 12288;    // 4096
    float* biasv  = wsf + 16384;    // 64

    build_keys<<<64, 64, 0, stream>>>(embed, ff_w1, ff_b1, ff_w2, ff_b2, ln_w, ln_b, keytab);
    build_tables<<<64, 64, 0, stream>>>(keytab, read_w, read_b, out_w, out_b,
                                        Gg, GhatN, Wc, biasv);
    delta_scan<<<256, 64, 0, stream>>>(seq, Gg, GhatN, keytab, Wc, biasv, out);
}